// Round 1
// baseline (360.656 us; speedup 1.0000x reference)
//
#include <hip/hip_runtime.h>

#define BS 4
#define CCH 64
#define HH 256
#define WW 256
#define DH (HH / BS)   // 64
#define DW (WW / BS)   // 64
#define WAVES 8        // 512 threads/block

// One block per (b, oh) output row; lane = ow; wave covers 8 channels.
__global__ __launch_bounds__(512, 4) void s2p_kernel(
    const float* __restrict__ in,
    const int* __restrict__ dir_p,
    float* __restrict__ out)
{
    const int dir  = *dir_p;                 // uniform
    const int blk  = blockIdx.x;             // b*DH + oh
    const int oh   = blk & (DH - 1);
    const int t    = threadIdx.x;
    const int wave = t >> 6;
    const int lane = t & 63;                 // ow

    float num = 0.f, den = 0.f;

    const float4* __restrict__ base = reinterpret_cast<const float4*>(in);
    // float4 index of x[b, c, h, lane*4] = ((b*CCH + c)*HH + h) * (WW/4) + lane
    const int c0 = wave * (CCH / WAVES);
    size_t rowbase = ((size_t)(blk >> 6) * CCH + c0) * HH + (size_t)oh * BS;
    rowbase = rowbase * (WW / 4) + lane;

    #pragma unroll
    for (int cc = 0; cc < CCH / WAVES; ++cc) {
        #pragma unroll
        for (int i = 0; i < BS; ++i) {
            float4 v = base[rowbase + (size_t)(cc * HH + i) * (WW / 4)];
            const float add_i = (float)i;
            float vals[4] = {v.x, v.y, v.z, v.w};
            #pragma unroll
            for (int j = 0; j < 4; ++j) {
                float add = (dir == 1) ? add_i : (float)j;   // h%4==i, w%4==j
                float x = vals[j];
                float y = (x < 0.f) ? (x + add) : x;
                num += y;
                den += (y > 0.f) ? 1.f : y;
            }
        }
    }

    __shared__ float s_num[WAVES][64];
    __shared__ float s_den[WAVES][64];
    s_num[wave][lane] = num;
    s_den[wave][lane] = den;
    __syncthreads();

    if (t < 64) {
        float n = 0.f, d = 1.f;
        #pragma unroll
        for (int w = 0; w < WAVES; ++w) {
            n += s_num[w][t];
            d += s_den[w][t];
        }
        out[(size_t)blk * DW + t] = n / d;
    }
}

extern "C" void kernel_launch(void* const* d_in, const int* in_sizes, int n_in,
                              void* d_out, int out_size, void* d_ws, size_t ws_size,
                              hipStream_t stream) {
    const float* in  = (const float*)d_in[0];
    const int*   dir = (const int*)d_in[1];
    float*       out = (float*)d_out;

    const int nblocks = 16 * DH;   // B * DH = 1024
    s2p_kernel<<<nblocks, 512, 0, stream>>>(in, dir, out);
}

// Round 3
// 332.146 us; speedup vs baseline: 1.0858x; 1.0858x over previous
//
#include <hip/hip_runtime.h>

#define BS 4
#define CCH 64
#define HH 256
#define WW 256
#define DH (HH / BS)   // 64
#define DW (WW / BS)   // 64
#define WAVES 8        // 512 threads/block

typedef float f32x4 __attribute__((ext_vector_type(4)));

// One block per (b, oh) output row; lane = ow; wave covers 8 channels.
// Full occupancy target: 8 waves/EU -> VGPR <= 64, 4 blocks/CU, 1024 blocks
// == exactly one full-device residency (256 CU x 32 waves).
__global__ __launch_bounds__(512, 8) void s2p_kernel(
    const float* __restrict__ in,
    const int* __restrict__ dir_p,
    float* __restrict__ out)
{
    const int dir  = *dir_p;                 // uniform
    const int blk  = blockIdx.x;             // b*DH + oh
    const int oh   = blk & (DH - 1);
    const int b    = blk >> 6;
    const int t    = threadIdx.x;
    const int wave = t >> 6;
    const int lane = t & 63;                 // ow

    const f32x4* __restrict__ base = reinterpret_cast<const f32x4*>(in);
    const int c0 = wave * (CCH / WAVES);
    // float4 index of x[b, c0, oh*4, lane*4]
    int idx = ((b * CCH + c0) * HH + oh * BS) * (WW / 4) + lane;

    float num = 0.f, den = 0.f;

    #pragma unroll 2
    for (int cc = 0; cc < CCH / WAVES; ++cc) {
        // 4 contiguous rows (4 KB/wave), read-once -> nontemporal
        f32x4 v0 = __builtin_nontemporal_load(&base[idx + 0 * (WW / 4)]);
        f32x4 v1 = __builtin_nontemporal_load(&base[idx + 1 * (WW / 4)]);
        f32x4 v2 = __builtin_nontemporal_load(&base[idx + 2 * (WW / 4)]);
        f32x4 v3 = __builtin_nontemporal_load(&base[idx + 3 * (WW / 4)]);
        idx += HH * (WW / 4);

        f32x4 vv[4] = {v0, v1, v2, v3};
        #pragma unroll
        for (int i = 0; i < 4; ++i) {
            const float add_i = (float)i;
            #pragma unroll
            for (int j = 0; j < 4; ++j) {
                float add = (dir == 1) ? add_i : (float)j;   // h%4==i, w%4==j
                float x = vv[i][j];
                float y = (x < 0.f) ? (x + add) : x;
                num += y;
                den += (y > 0.f) ? 1.f : y;
            }
        }
    }

    __shared__ float s_num[WAVES][64];
    __shared__ float s_den[WAVES][64];
    s_num[wave][lane] = num;
    s_den[wave][lane] = den;
    __syncthreads();

    if (t < 64) {
        float n = 0.f, d = 1.f;
        #pragma unroll
        for (int w = 0; w < WAVES; ++w) {
            n += s_num[w][t];
            d += s_den[w][t];
        }
        out[(size_t)blk * DW + t] = n / d;
    }
}

extern "C" void kernel_launch(void* const* d_in, const int* in_sizes, int n_in,
                              void* d_out, int out_size, void* d_ws, size_t ws_size,
                              hipStream_t stream) {
    const float* in  = (const float*)d_in[0];
    const int*   dir = (const int*)d_in[1];
    float*       out = (float*)d_out;

    const int nblocks = 16 * DH;   // B * DH = 1024
    s2p_kernel<<<nblocks, 512, 0, stream>>>(in, dir, out);
}